// Round 7
// baseline (178.685 us; speedup 1.0000x reference)
//
#include <hip/hip_runtime.h>
#include <hip/hip_fp16.h>
#include <math.h>

#define KDIM 256
#define NITER 50

// ws byte layout:
// [0, 67108864)   CT fp16: CT[b][j][i] = C[b][i][j]   (512 * 256 * 256 halves)
// then floats: psum[2048], ptrace[2048], pmin[2048], prs[2048*256], lossB[512]

__global__ __launch_bounds__(256, 8) void k1_stream(
    const float* __restrict__ scores, const float* __restrict__ C,
    __half* __restrict__ CT,
    float* __restrict__ psum_o, float* __restrict__ ptrace_o, float* __restrict__ pmin_o)
{
    const int blk = blockIdx.x;
    const int b = blk >> 2, chunk = blk & 3;
    const int tid = threadIdx.x, lane = tid & 63, wave = tid >> 6;
    const float4* C4 = (const float4*)(C + (size_t)b * KDIM * KDIM);
    __half* CTb = CT + (size_t)b * KDIM * KDIM;

    __shared__ float sf[KDIM];
    __shared__ __half tile[64][34];     // [j-local][i-local(32)+pad]
    __shared__ float redS[256], redT[256], redM[256];

    sf[tid] = 0.5f * scores[b*KDIM + tid];
    __syncthreads();

    const int c0 = lane * 4;
    const float fj0 = sf[c0], fj1 = sf[c0+1], fj2 = sf[c0+2], fj3 = sf[c0+3];
    const int jg_own = lane >> 4;       // which j-group (64-wide) this lane's 4 columns belong to
    const int l16 = lane & 15;

    float psum = 0.f, ptrace = 0.f, pmin = INFINITY;
    #pragma unroll
    for (int p = 0; p < 2; ++p) {
        __half2 st01[8], st23[8];
        #pragma unroll
        for (int itL = 0; itL < 8; ++itL) {
            const int it = p*8 + itL;
            const int row = chunk*64 + it*4 + wave;     // i index
            float4 c4 = C4[row*(KDIM/4) + lane];
            const float frow = sf[row];
            psum += (c4.x + c4.y) + (c4.z + c4.w);
            pmin = fminf(pmin, fminf(fminf(frow+fj0+c4.x, frow+fj1+c4.y),
                                     fminf(frow+fj2+c4.z, frow+fj3+c4.w)));
            if ((row >> 2) == lane) {
                int r2 = row & 3;
                ptrace += (r2==0)?c4.x:(r2==1)?c4.y:(r2==2)?c4.z:c4.w;
            }
            __half2 h01, h23;
            h01.x = __float2half_rn(c4.x); h01.y = __float2half_rn(c4.y);
            h23.x = __float2half_rn(c4.z); h23.y = __float2half_rn(c4.w);
            st01[itL] = h01; st23[itL] = h23;
        }
        // transpose p's 32-i-wide slab, one 64-j group at a time
        #pragma unroll
        for (int g = 0; g < 4; ++g) {
            __syncthreads();
            if (jg_own == g) {
                const int jl = l16 * 4;
                #pragma unroll
                for (int itL = 0; itL < 8; ++itL) {
                    const int il = itL*4 + wave;       // 0..31
                    tile[jl+0][il] = st01[itL].x;
                    tile[jl+1][il] = st01[itL].y;
                    tile[jl+2][il] = st23[itL].x;
                    tile[jl+3][il] = st23[itL].y;
                }
            }
            __syncthreads();
            // write out 64 j-rows x 32 halves, coalesced 16B stores
            const int jl = tid >> 2, il0 = (tid & 3) * 8;
            const uint* src = (const uint*)&tile[jl][il0];    // 4B-aligned
            uint4 v; v.x = src[0]; v.y = src[1]; v.z = src[2]; v.w = src[3];
            const int j = g*64 + jl;
            __half* dst = CTb + j*KDIM + chunk*64 + p*32 + il0;   // 16B-aligned
            *(uint4*)dst = v;
        }
    }

    redS[tid] = psum; redT[tid] = ptrace; redM[tid] = pmin;
    __syncthreads();
    for (int s = 128; s > 0; s >>= 1) {
        if (tid < s) {
            redS[tid] += redS[tid+s];
            redT[tid] += redT[tid+s];
            redM[tid]  = fminf(redM[tid], redM[tid+s]);
        }
        __syncthreads();
    }
    if (tid == 0) { psum_o[blk] = redS[0]; ptrace_o[blk] = redT[0]; pmin_o[blk] = redM[0]; }
}

__global__ __launch_bounds__(256, 8) void k2_rowsums(
    const float* __restrict__ scores, const __half* __restrict__ CT,
    const float* __restrict__ psum_i, const float* __restrict__ ptrace_i, const float* __restrict__ pmin_i,
    float* __restrict__ prs)
{
    const int blk = (int)gridDim.x - 1 - (int)blockIdx.x;   // reverse: chase k1's freshest writes
    const int b = blk >> 2, jc = blk & 3;
    const int tid = threadIdx.x, lane = tid & 63, wave = tid >> 6;
    const __half* CTb = CT + (size_t)b * KDIM * KDIM;

    __shared__ float sf[KDIM];
    __shared__ float part[12];
    __shared__ float bc2[2];
    __shared__ float racc[4][KDIM];

    sf[tid] = 0.5f * scores[b*KDIM + tid];
    if (tid < 12) {
        part[tid] = (tid < 4) ? psum_i[b*4+tid]
                  : (tid < 8) ? ptrace_i[b*4+tid-4]
                              : pmin_i[b*4+tid-8];
    }
    __syncthreads();
    if (tid == 0) {
        float s = part[0]+part[1]+part[2]+part[3];
        float t = part[4]+part[5]+part[6]+part[7];
        float mn = fminf(fminf(part[8],part[9]), fminf(part[10],part[11]));
        bc2[0] = mn;
        bc2[1] = fmaxf((s - t) / (float)(KDIM*KDIM - KDIM), 1e-8f);
    }
    __syncthreads();
    const float minv = bc2[0];
    const float inv_eps = 1.0f / bc2[1];

    const int i0 = lane * 4;
    const float fi0 = sf[i0], fi1 = sf[i0+1], fi2 = sf[i0+2], fi3 = sf[i0+3];
    float a0 = 0.f, a1 = 0.f, a2 = 0.f, a3 = 0.f;
    #pragma unroll
    for (int it = 0; it < 16; ++it) {
        const int j = jc*64 + it*4 + wave;
        const __half2* p2 = (const __half2*)(CTb + j*KDIM + i0);   // coalesced 8B/lane
        __half2 h01 = p2[0], h23 = p2[1];
        const float base = minv - sf[j];
        a0 += __expf((base - fi0 - __half2float(h01.x)) * inv_eps);
        a1 += __expf((base - fi1 - __half2float(h01.y)) * inv_eps);
        a2 += __expf((base - fi2 - __half2float(h23.x)) * inv_eps);
        a3 += __expf((base - fi3 - __half2float(h23.y)) * inv_eps);
    }
    racc[wave][i0+0] = a0; racc[wave][i0+1] = a1;
    racc[wave][i0+2] = a2; racc[wave][i0+3] = a3;
    __syncthreads();
    prs[(size_t)blk*KDIM + tid] = racc[0][tid]+racc[1][tid]+racc[2][tid]+racc[3][tid];
}

__global__ __launch_bounds__(256) void k3_fw(
    const float* __restrict__ scores, const int* __restrict__ targets,
    const __half* __restrict__ CT,
    const float* __restrict__ psum_i, const float* __restrict__ ptrace_i, const float* __restrict__ pmin_i,
    const float* __restrict__ prs, float* __restrict__ lossB)
{
    const int b = blockIdx.x;
    const int tid = threadIdx.x, lane = tid & 63, wave = tid >> 6;
    const __half* CTb = CT + (size_t)b * KDIM * KDIM;

    __shared__ float sf[KDIM];
    __shared__ float part[12];
    __shared__ float bc2[2];
    __shared__ float rsL[KDIM];
    __shared__ float aAll[KDIM];
    __shared__ int   wcnt[4];
    __shared__ int   sIdx[64];
    __shared__ float sLog[64];
    __shared__ float wm[4], wsm[4];

    sf[tid] = 0.5f * scores[b*KDIM + tid];
    if (tid < 12) {
        part[tid] = (tid < 4) ? psum_i[b*4+tid]
                  : (tid < 8) ? ptrace_i[b*4+tid-4]
                              : pmin_i[b*4+tid-8];
    }
    rsL[tid] = prs[(size_t)(b*4+0)*KDIM+tid] + prs[(size_t)(b*4+1)*KDIM+tid]
             + prs[(size_t)(b*4+2)*KDIM+tid] + prs[(size_t)(b*4+3)*KDIM+tid];
    __syncthreads();
    if (tid == 0) {
        float s = part[0]+part[1]+part[2]+part[3];
        float t = part[4]+part[5]+part[6]+part[7];
        float mn = fminf(fminf(part[8],part[9]), fminf(part[10],part[11]));
        bc2[0] = mn;
        bc2[1] = fmaxf((s - t) / (float)(KDIM*KDIM - KDIM), 1e-8f);
    }
    __syncthreads();
    const float minv = bc2[0];
    const float eps = bc2[1];
    const float inv_eps = 1.0f / eps;

    // ---------- FW on wave 0: lane owns rows {lane, lane+64, lane+128, lane+192} ----------
    if (wave == 0) {
        const float f0 = sf[lane], f1 = sf[lane+64], f2 = sf[lane+128], f3 = sf[lane+192];

        float v = rsL[lane]; int vi = lane;
        float t;
        t = rsL[lane+64];  if (t < v) { v = t; vi = lane+64; }
        t = rsL[lane+128]; if (t < v) { v = t; vi = lane+128; }
        t = rsL[lane+192]; if (t < v) { v = t; vi = lane+192; }
        #pragma unroll
        for (int off = 32; off > 0; off >>= 1) {
            float ov = __shfl_xor(v, off);
            int  ovi = __shfl_xor(vi, off);
            if (ov < v || (ov == v && ovi < vi)) { v = ov; vi = ovi; }
        }
        const int idx0 = vi;

        const __half* col0 = CTb + (size_t)idx0 * KDIM;
        float fidx = sf[idx0];
        float g0 = 2.0f * __expf((minv - (f0 + fidx + __half2float(col0[lane    ]))) * inv_eps);
        float g1 = 2.0f * __expf((minv - (f1 + fidx + __half2float(col0[lane+64 ]))) * inv_eps);
        float g2 = 2.0f * __expf((minv - (f2 + fidx + __half2float(col0[lane+128]))) * inv_eps);
        float g3 = 2.0f * __expf((minv - (f3 + fidx + __half2float(col0[lane+192]))) * inv_eps);
        float a0 = (lane     == idx0) ? 1.0f : 0.0f;
        float a1 = (lane+64  == idx0) ? 1.0f : 0.0f;
        float a2 = (lane+128 == idx0) ? 1.0f : 0.0f;
        float a3 = (lane+192 == idx0) ? 1.0f : 0.0f;

        for (int it = 1; it < NITER; ++it) {
            float v2 = g0; int vi2 = lane;
            if (g1 < v2) { v2 = g1; vi2 = lane+64; }
            if (g2 < v2) { v2 = g2; vi2 = lane+128; }
            if (g3 < v2) { v2 = g3; vi2 = lane+192; }
            #pragma unroll
            for (int off = 32; off > 0; off >>= 1) {
                float ov = __shfl_xor(v2, off);
                int  ovi = __shfl_xor(vi2, off);
                if (ov < v2 || (ov == v2 && ovi < vi2)) { v2 = ov; vi2 = ovi; }
            }
            const int idx = vi2;
            const float gamma = 2.0f / ((float)it + 2.0f);
            const float omg = 1.0f - gamma;
            const int which = idx >> 6;
            float fsel = (which==0) ? f0 : (which==1) ? f1 : (which==2) ? f2 : f3;
            const float fidx2 = __shfl(fsel, idx & 63);
            const __half* col = CTb + (size_t)idx * KDIM;     // contiguous 512B: no line amplification
            const float cc0 = __half2float(col[lane    ]);
            const float cc1 = __half2float(col[lane+64 ]);
            const float cc2 = __half2float(col[lane+128]);
            const float cc3 = __half2float(col[lane+192]);
            g0 = omg*g0 + 2.0f*gamma*__expf((minv - (f0 + fidx2 + cc0)) * inv_eps);
            g1 = omg*g1 + 2.0f*gamma*__expf((minv - (f1 + fidx2 + cc1)) * inv_eps);
            g2 = omg*g2 + 2.0f*gamma*__expf((minv - (f2 + fidx2 + cc2)) * inv_eps);
            g3 = omg*g3 + 2.0f*gamma*__expf((minv - (f3 + fidx2 + cc3)) * inv_eps);
            a0 = omg*a0 + ((lane     == idx) ? gamma : 0.0f);
            a1 = omg*a1 + ((lane+64  == idx) ? gamma : 0.0f);
            a2 = omg*a2 + ((lane+128 == idx) ? gamma : 0.0f);
            a3 = omg*a3 + ((lane+192 == idx) ? gamma : 0.0f);
        }
        aAll[lane]     = a0;
        aAll[lane+64]  = a1;
        aAll[lane+128] = a2;
        aAll[lane+192] = a3;
    }
    __syncthreads();

    const float a = aAll[tid];

    // ---------- support collection via ballot compaction (<=50, tid-ordered) ----------
    unsigned long long mask = __ballot(a > 0.f);
    if (lane == 0) wcnt[wave] = __popcll(mask);
    __syncthreads();
    int off0 = 0;
    for (int w = 0; w < wave; ++w) off0 += wcnt[w];
    const int count = wcnt[0] + wcnt[1] + wcnt[2] + wcnt[3];
    if (a > 0.f) {
        int pos = off0 + __popcll(mask & ((1ull << lane) - 1ull));
        sIdx[pos] = tid;
        sLog[pos] = logf(a);
    }
    __syncthreads();

    // ---------- logsumexp over support pairs (C_ij = CT[j][i]) ----------
    float m = -INFINITY, ss = 0.f;
    const int total = count * count;
    for (int p = tid; p < total; p += KDIM) {
        int ii = p / count;
        int jj = p - ii * count;
        int i = sIdx[ii], j = sIdx[jj];
        float cij = __half2float(CTb[(size_t)j*KDIM + i]);
        float lm = (minv - (sf[i] + sf[j] + cij)) * inv_eps;
        float tt = sLog[ii] + sLog[jj] + lm;
        if (tt > m) { ss = ss * __expf(m - tt) + 1.0f; m = tt; }
        else        { ss += __expf(tt - m); }
    }
    #pragma unroll
    for (int off = 32; off > 0; off >>= 1) {
        float om = __shfl_xor(m, off);
        float os = __shfl_xor(ss, off);
        if (os > 0.f) {
            if (ss <= 0.f)   { m = om; ss = os; }
            else if (om > m) { ss = ss*__expf(m-om) + os; m = om; }
            else             { ss += os*__expf(om-m); }
        }
    }
    if (lane == 0) { wm[wave] = m; wsm[wave] = ss; }
    __syncthreads();
    if (tid == 0) {
        float M = wm[0], S = wsm[0];
        #pragma unroll
        for (int w = 1; w < 4; ++w) {
            float om = wm[w], os = wsm[w];
            if (os > 0.f) {
                if (S <= 0.f)    { M = om; S = os; }
                else if (om > M) { S = S*__expf(M-om) + os; M = om; }
                else             { S += os*__expf(om-M); }
            }
        }
        float logval = M + logf(S);
        float shift = -minv * inv_eps;
        float conjugate = -eps * (logval + shift);
        float fy = scores[b*KDIM + targets[b]];
        lossB[b] = conjugate - fy;
    }
}

__global__ __launch_bounds__(512) void cacis_reduce(const float* __restrict__ lossB,
                                                    float* __restrict__ out, int B)
{
    __shared__ float red[512];
    int t = threadIdx.x;
    red[t] = (t < B) ? lossB[t] : 0.f;
    __syncthreads();
    for (int s = 256; s > 0; s >>= 1) { if (t < s) red[t] += red[t+s]; __syncthreads(); }
    if (t == 0) out[0] = red[0] / (float)B;
}

extern "C" void kernel_launch(void* const* d_in, const int* in_sizes, int n_in,
                              void* d_out, int out_size, void* d_ws, size_t ws_size,
                              hipStream_t stream) {
    const float* scores  = (const float*)d_in[0];
    const int*   targets = (const int*)d_in[1];
    const float* C       = (const float*)d_in[2];
    float* out = (float*)d_out;
    const int B = in_sizes[1];   // 512

    __half* CT  = (__half*)d_ws;                                   // 67108864 bytes
    float* wsf  = (float*)((char*)d_ws + (size_t)67108864);
    float* psum   = wsf;
    float* ptrace = wsf + 2048;
    float* pmin   = wsf + 4096;
    float* prs    = wsf + 6144;                                    // 2048*256 floats
    float* lossB  = wsf + 6144 + 524288;

    k1_stream <<<B*4, 256, 0, stream>>>(scores, C, CT, psum, ptrace, pmin);
    k2_rowsums<<<B*4, 256, 0, stream>>>(scores, CT, psum, ptrace, pmin, prs);
    k3_fw     <<<B,   256, 0, stream>>>(scores, targets, CT, psum, ptrace, pmin, prs, lossB);
    cacis_reduce<<<1, 512, 0, stream>>>(lossB, out, B);
}

// Round 8
// 110.082 us; speedup vs baseline: 1.6232x; 1.6232x over previous
//
#include <hip/hip_runtime.h>
#include <hip/hip_fp16.h>
#include <math.h>

#define KDIM 256
#define NITER 50
#define REG_H 8192   // halves per (b,chunk,p) region: 256 j * 32 il

// CT3 layout: region r = (b*4+chunk)*2 + p ; within region: [j][il32] halves.
// C[b][i][j] == CT3[ ((b*4+(i>>6))*2 + ((i>>5)&1))*REG_H + j*32 + (i&31) ]

__global__ __launch_bounds__(256, 7) void k1_stream(
    const float* __restrict__ scores, const float* __restrict__ C,
    __half* __restrict__ CT,
    float* __restrict__ psum_o, float* __restrict__ ptrace_o, float* __restrict__ pmin_o)
{
    const int blk = blockIdx.x;
    const int b = blk >> 2, chunk = blk & 3;
    const int tid = threadIdx.x, lane = tid & 63, wave = tid >> 6;
    const float4* C4 = (const float4*)(C + (size_t)b * KDIM * KDIM);
    __half* CTb = CT + (size_t)((b*4 + chunk) * 2) * REG_H;

    __shared__ float sf[KDIM];
    __shared__ __half T[32 * 264];          // [sl][j], j-stride 264 (padded)
    __shared__ float redS[256], redT[256], redM[256];

    sf[tid] = 0.5f * scores[b*KDIM + tid];
    __syncthreads();

    const int j0 = lane * 4;
    const float fj0 = sf[j0], fj1 = sf[j0+1], fj2 = sf[j0+2], fj3 = sf[j0+3];

    float psum = 0.f, ptrace = 0.f, pmin = INFINITY;

    #pragma unroll
    for (int p = 0; p < 2; ++p) {
        #pragma unroll
        for (int it = 0; it < 8; ++it) {
            const int sl  = it*4 + wave;            // 0..31 (slab-local row)
            const int row = chunk*64 + p*32 + sl;   // global i
            float4 c4 = C4[row*(KDIM/4) + lane];
            const float frow = sf[row];
            psum += (c4.x + c4.y) + (c4.z + c4.w);
            pmin = fminf(pmin, fminf(fminf(frow+fj0+c4.x, frow+fj1+c4.y),
                                     fminf(frow+fj2+c4.z, frow+fj3+c4.w)));
            if ((row >> 2) == lane) {
                int r2 = row & 3;
                ptrace += (r2==0)?c4.x:(r2==1)?c4.y:(r2==2)?c4.z:c4.w;
            }
            __half2 h01, h23;
            h01.x = __float2half_rn(c4.x); h01.y = __float2half_rn(c4.y);
            h23.x = __float2half_rn(c4.z); h23.y = __float2half_rn(c4.w);
            *(__half2*)&T[sl*264 + j0    ] = h01;
            *(__half2*)&T[sl*264 + j0 + 2] = h23;
        }
        __syncthreads();
        // readout: thread tid owns output j = tid; writes 64B contiguous.
        {
            __half* dstBase = CTb + (size_t)p * REG_H + (size_t)tid * 32;
            #pragma unroll
            for (int v4 = 0; v4 < 4; ++v4) {
                uint w[4];
                #pragma unroll
                for (int dw = 0; dw < 4; ++dw) {
                    const int sl0 = v4*8 + dw*2;
                    const uint u0 = (uint)__half_as_ushort(T[(sl0  )*264 + tid]);
                    const uint u1 = (uint)__half_as_ushort(T[(sl0+1)*264 + tid]);
                    w[dw] = u0 | (u1 << 16);
                }
                uint4 v; v.x = w[0]; v.y = w[1]; v.z = w[2]; v.w = w[3];
                *(uint4*)(dstBase + v4*8) = v;
            }
        }
        __syncthreads();
    }

    redS[tid] = psum; redT[tid] = ptrace; redM[tid] = pmin;
    __syncthreads();
    for (int s = 128; s > 0; s >>= 1) {
        if (tid < s) {
            redS[tid] += redS[tid+s];
            redT[tid] += redT[tid+s];
            redM[tid]  = fminf(redM[tid], redM[tid+s]);
        }
        __syncthreads();
    }
    if (tid == 0) { psum_o[blk] = redS[0]; ptrace_o[blk] = redT[0]; pmin_o[blk] = redM[0]; }
}

__global__ __launch_bounds__(256, 6) void k2_rowsums(
    const float* __restrict__ scores, const __half* __restrict__ CT,
    const float* __restrict__ psum_i, const float* __restrict__ ptrace_i, const float* __restrict__ pmin_i,
    float* __restrict__ prs)
{
    const int blk = blockIdx.x;
    const int b = blk >> 2, jc = blk & 3;
    const int tid = threadIdx.x, lane = tid & 63, wave = tid >> 6;
    const __half* CTb = CT + (size_t)b * 8 * REG_H;

    __shared__ float sf[KDIM];
    __shared__ float part[12];
    __shared__ float bc2[2];
    __shared__ float racc[4][KDIM];

    sf[tid] = 0.5f * scores[b*KDIM + tid];
    if (tid < 12) {
        part[tid] = (tid < 4) ? psum_i[b*4+tid]
                  : (tid < 8) ? ptrace_i[b*4+tid-4]
                              : pmin_i[b*4+tid-8];
    }
    __syncthreads();
    if (tid == 0) {
        float s = part[0]+part[1]+part[2]+part[3];
        float t = part[4]+part[5]+part[6]+part[7];
        float mn = fminf(fminf(part[8],part[9]), fminf(part[10],part[11]));
        bc2[0] = mn;
        bc2[1] = fmaxf((s - t) / (float)(KDIM*KDIM - KDIM), 1e-8f);
    }
    __syncthreads();
    const float minv = bc2[0];
    const float inv_eps = 1.0f / bc2[1];

    const int slot = lane & 15;         // p(bit3) | ilv(bits0-2)
    const int jj   = lane >> 4;         // 0..3
    const int p    = slot >> 3;
    const int ilv  = slot & 7;

    float fi[4][4];
    #pragma unroll
    for (int c = 0; c < 4; ++c)
        #pragma unroll
        for (int r = 0; r < 4; ++r)
            fi[c][r] = sf[c*64 + slot*4 + r];

    float acc[4][4] = {{0.f}};
    #pragma unroll
    for (int c = 0; c < 4; ++c) {
        const __half* reg = CTb + (size_t)(c*2 + p) * REG_H;
        #pragma unroll
        for (int jg = 0; jg < 4; ++jg) {
            const int j = jc*64 + jg*16 + wave*4 + jj;
            const float mfj = minv - sf[j];
            const __half2* src = (const __half2*)(reg + (size_t)j*32 + ilv*4);
            __half2 h01 = src[0], h23 = src[1];
            acc[c][0] += __expf((mfj - fi[c][0] - __half2float(h01.x)) * inv_eps);
            acc[c][1] += __expf((mfj - fi[c][1] - __half2float(h01.y)) * inv_eps);
            acc[c][2] += __expf((mfj - fi[c][2] - __half2float(h23.x)) * inv_eps);
            acc[c][3] += __expf((mfj - fi[c][3] - __half2float(h23.y)) * inv_eps);
        }
    }
    // sum over jj (lane bits 4,5) within the wave
    #pragma unroll
    for (int c = 0; c < 4; ++c)
        #pragma unroll
        for (int r = 0; r < 4; ++r) {
            acc[c][r] += __shfl_xor(acc[c][r], 16);
            acc[c][r] += __shfl_xor(acc[c][r], 32);
        }
    if (lane < 16) {
        #pragma unroll
        for (int c = 0; c < 4; ++c)
            #pragma unroll
            for (int r = 0; r < 4; ++r)
                racc[wave][c*64 + lane*4 + r] = acc[c][r];
    }
    __syncthreads();
    prs[(size_t)blk*KDIM + tid] = racc[0][tid]+racc[1][tid]+racc[2][tid]+racc[3][tid];
}

__global__ __launch_bounds__(256) void k3_fw(
    const float* __restrict__ scores, const int* __restrict__ targets,
    const __half* __restrict__ CT,
    const float* __restrict__ psum_i, const float* __restrict__ ptrace_i, const float* __restrict__ pmin_i,
    const float* __restrict__ prs, float* __restrict__ lossB)
{
    const int b = blockIdx.x;
    const int tid = threadIdx.x, lane = tid & 63, wave = tid >> 6;
    const __half* CTb = CT + (size_t)b * 8 * REG_H;

    __shared__ float sf[KDIM];
    __shared__ float part[12];
    __shared__ float bc2[2];
    __shared__ float rsL[KDIM];
    __shared__ float aAll[KDIM];
    __shared__ int   wcnt[4];
    __shared__ int   sIdx[64];
    __shared__ float sLog[64];
    __shared__ float wm[4], wsm[4];

    sf[tid] = 0.5f * scores[b*KDIM + tid];
    if (tid < 12) {
        part[tid] = (tid < 4) ? psum_i[b*4+tid]
                  : (tid < 8) ? ptrace_i[b*4+tid-4]
                              : pmin_i[b*4+tid-8];
    }
    rsL[tid] = prs[(size_t)(b*4+0)*KDIM+tid] + prs[(size_t)(b*4+1)*KDIM+tid]
             + prs[(size_t)(b*4+2)*KDIM+tid] + prs[(size_t)(b*4+3)*KDIM+tid];
    __syncthreads();
    if (tid == 0) {
        float s = part[0]+part[1]+part[2]+part[3];
        float t = part[4]+part[5]+part[6]+part[7];
        float mn = fminf(fminf(part[8],part[9]), fminf(part[10],part[11]));
        bc2[0] = mn;
        bc2[1] = fmaxf((s - t) / (float)(KDIM*KDIM - KDIM), 1e-8f);
    }
    __syncthreads();
    const float minv = bc2[0];
    const float eps = bc2[1];
    const float inv_eps = 1.0f / eps;

    // ---------- FW on wave 0: lane owns rows i = c*64 + lane ----------
    if (wave == 0) {
        const float f0 = sf[lane], f1 = sf[lane+64], f2 = sf[lane+128], f3 = sf[lane+192];
        // per-lane column-gather bases: region (c*2 + lane>>5), offset (lane&31)
        const __half* g0p = CTb + (size_t)(0*2 + (lane>>5))*REG_H + (lane&31);
        const __half* g1p = CTb + (size_t)(1*2 + (lane>>5))*REG_H + (lane&31);
        const __half* g2p = CTb + (size_t)(2*2 + (lane>>5))*REG_H + (lane&31);
        const __half* g3p = CTb + (size_t)(3*2 + (lane>>5))*REG_H + (lane&31);

        float v = rsL[lane]; int vi = lane;
        float t;
        t = rsL[lane+64];  if (t < v) { v = t; vi = lane+64; }
        t = rsL[lane+128]; if (t < v) { v = t; vi = lane+128; }
        t = rsL[lane+192]; if (t < v) { v = t; vi = lane+192; }
        #pragma unroll
        for (int off = 32; off > 0; off >>= 1) {
            float ov = __shfl_xor(v, off);
            int  ovi = __shfl_xor(vi, off);
            if (ov < v || (ov == v && ovi < vi)) { v = ov; vi = ovi; }
        }
        const int idx0 = vi;

        float fidx = sf[idx0];
        float g0 = 2.0f * __expf((minv - (f0 + fidx + __half2float(g0p[(size_t)idx0*32]))) * inv_eps);
        float g1 = 2.0f * __expf((minv - (f1 + fidx + __half2float(g1p[(size_t)idx0*32]))) * inv_eps);
        float g2 = 2.0f * __expf((minv - (f2 + fidx + __half2float(g2p[(size_t)idx0*32]))) * inv_eps);
        float g3 = 2.0f * __expf((minv - (f3 + fidx + __half2float(g3p[(size_t)idx0*32]))) * inv_eps);
        float a0 = (lane     == idx0) ? 1.0f : 0.0f;
        float a1 = (lane+64  == idx0) ? 1.0f : 0.0f;
        float a2 = (lane+128 == idx0) ? 1.0f : 0.0f;
        float a3 = (lane+192 == idx0) ? 1.0f : 0.0f;

        for (int it = 1; it < NITER; ++it) {
            float v2 = g0; int vi2 = lane;
            if (g1 < v2) { v2 = g1; vi2 = lane+64; }
            if (g2 < v2) { v2 = g2; vi2 = lane+128; }
            if (g3 < v2) { v2 = g3; vi2 = lane+192; }
            #pragma unroll
            for (int off = 32; off > 0; off >>= 1) {
                float ov = __shfl_xor(v2, off);
                int  ovi = __shfl_xor(vi2, off);
                if (ov < v2 || (ov == v2 && ovi < vi2)) { v2 = ov; vi2 = ovi; }
            }
            const int idx = vi2;
            const float gamma = 2.0f / ((float)it + 2.0f);
            const float omg = 1.0f - gamma;
            const int which = idx >> 6;
            float fsel = (which==0) ? f0 : (which==1) ? f1 : (which==2) ? f2 : f3;
            const float fidx2 = __shfl(fsel, idx & 63);
            const size_t co = (size_t)idx * 32;
            const float cc0 = __half2float(g0p[co]);
            const float cc1 = __half2float(g1p[co]);
            const float cc2 = __half2float(g2p[co]);
            const float cc3 = __half2float(g3p[co]);
            g0 = omg*g0 + 2.0f*gamma*__expf((minv - (f0 + fidx2 + cc0)) * inv_eps);
            g1 = omg*g1 + 2.0f*gamma*__expf((minv - (f1 + fidx2 + cc1)) * inv_eps);
            g2 = omg*g2 + 2.0f*gamma*__expf((minv - (f2 + fidx2 + cc2)) * inv_eps);
            g3 = omg*g3 + 2.0f*gamma*__expf((minv - (f3 + fidx2 + cc3)) * inv_eps);
            a0 = omg*a0 + ((lane     == idx) ? gamma : 0.0f);
            a1 = omg*a1 + ((lane+64  == idx) ? gamma : 0.0f);
            a2 = omg*a2 + ((lane+128 == idx) ? gamma : 0.0f);
            a3 = omg*a3 + ((lane+192 == idx) ? gamma : 0.0f);
        }
        aAll[lane]     = a0;
        aAll[lane+64]  = a1;
        aAll[lane+128] = a2;
        aAll[lane+192] = a3;
    }
    __syncthreads();

    const float a = aAll[tid];

    // ---------- support collection via ballot compaction (<=50, tid-ordered) ----------
    unsigned long long mask = __ballot(a > 0.f);
    if (lane == 0) wcnt[wave] = __popcll(mask);
    __syncthreads();
    int off0 = 0;
    for (int w = 0; w < wave; ++w) off0 += wcnt[w];
    const int count = wcnt[0] + wcnt[1] + wcnt[2] + wcnt[3];
    if (a > 0.f) {
        int pos = off0 + __popcll(mask & ((1ull << lane) - 1ull));
        sIdx[pos] = tid;
        sLog[pos] = logf(a);
    }
    __syncthreads();

    // ---------- logsumexp over support pairs ----------
    float m = -INFINITY, ss = 0.f;
    const int total = count * count;
    for (int p = tid; p < total; p += KDIM) {
        int ii = p / count;
        int jj = p - ii * count;
        int i = sIdx[ii], j = sIdx[jj];
        float cij = __half2float(CTb[(size_t)((i>>6)*2 + ((i>>5)&1))*REG_H + (size_t)j*32 + (i&31)]);
        float lm = (minv - (sf[i] + sf[j] + cij)) * inv_eps;
        float tt = sLog[ii] + sLog[jj] + lm;
        if (tt > m) { ss = ss * __expf(m - tt) + 1.0f; m = tt; }
        else        { ss += __expf(tt - m); }
    }
    #pragma unroll
    for (int off = 32; off > 0; off >>= 1) {
        float om = __shfl_xor(m, off);
        float os = __shfl_xor(ss, off);
        if (os > 0.f) {
            if (ss <= 0.f)   { m = om; ss = os; }
            else if (om > m) { ss = ss*__expf(m-om) + os; m = om; }
            else             { ss += os*__expf(om-m); }
        }
    }
    if (lane == 0) { wm[wave] = m; wsm[wave] = ss; }
    __syncthreads();
    if (tid == 0) {
        float M = wm[0], S = wsm[0];
        #pragma unroll
        for (int w = 1; w < 4; ++w) {
            float om = wm[w], os = wsm[w];
            if (os > 0.f) {
                if (S <= 0.f)    { M = om; S = os; }
                else if (om > M) { S = S*__expf(M-om) + os; M = om; }
                else             { S += os*__expf(om-M); }
            }
        }
        float logval = M + logf(S);
        float shift = -minv * inv_eps;
        float conjugate = -eps * (logval + shift);
        float fy = scores[b*KDIM + targets[b]];
        lossB[b] = conjugate - fy;
    }
}

__global__ __launch_bounds__(512) void cacis_reduce(const float* __restrict__ lossB,
                                                    float* __restrict__ out, int B)
{
    __shared__ float red[512];
    int t = threadIdx.x;
    red[t] = (t < B) ? lossB[t] : 0.f;
    __syncthreads();
    for (int s = 256; s > 0; s >>= 1) { if (t < s) red[t] += red[t+s]; __syncthreads(); }
    if (t == 0) out[0] = red[0] / (float)B;
}

extern "C" void kernel_launch(void* const* d_in, const int* in_sizes, int n_in,
                              void* d_out, int out_size, void* d_ws, size_t ws_size,
                              hipStream_t stream) {
    const float* scores  = (const float*)d_in[0];
    const int*   targets = (const int*)d_in[1];
    const float* C       = (const float*)d_in[2];
    float* out = (float*)d_out;
    const int B = in_sizes[1];   // 512

    __half* CT  = (__half*)d_ws;                                   // 67108864 bytes
    float* wsf  = (float*)((char*)d_ws + (size_t)67108864);
    float* psum   = wsf;
    float* ptrace = wsf + 2048;
    float* pmin   = wsf + 4096;
    float* prs    = wsf + 6144;                                    // 2048*256 floats
    float* lossB  = wsf + 6144 + 524288;

    k1_stream <<<B*4, 256, 0, stream>>>(scores, C, CT, psum, ptrace, pmin);
    k2_rowsums<<<B*4, 256, 0, stream>>>(scores, CT, psum, ptrace, pmin, prs);
    k3_fw     <<<B,   256, 0, stream>>>(scores, targets, CT, psum, ptrace, pmin, prs, lossB);
    cacis_reduce<<<1, 512, 0, stream>>>(lossB, out, B);
}